// Round 3
// baseline (419.282 us; speedup 1.0000x reference)
//
#include <hip/hip_runtime.h>
#include <math.h>

// Problem constants
#define CCH   640          // channels
#define MM    25           // m = 5*5 spatial
#define NB    4096         // query batch
#define WSR   25           // way*shot prototype rows
#define ROWF  16000        // CCH*MM floats per row
#define SLAB  (NB*CCH)     // 2,621,440 floats = one output slab (per w)

static __device__ __forceinline__ void load4(float* dst, const float* p) {
  __builtin_memcpy(dst, p, 16);
}

// ---------------------------------------------------------------------------
// rowmean: one thread per (b,c); 25 dense floats per thread; no LDS.
// ---------------------------------------------------------------------------
__global__ __launch_bounds__(256) void rowmean_k(const float* __restrict__ src,
                                                 float* __restrict__ dst, int n) {
  int idx = blockIdx.x * 256 + threadIdx.x;   // idx = b*CCH + c
  if (idx >= n) return;
  int b = idx / CCH, c = idx - b * CCH;
  const float* p = src + (size_t)b * ROWF + c * MM;
  float s = 0.f;
  float v[4];
  #pragma unroll
  for (int j = 0; j < 6; ++j) {
    load4(v, p + 4*j);
    s += (v[0] + v[1]) + (v[2] + v[3]);
  }
  s += p[24];
  dst[idx] = s * (1.f/25.f);
}

// ---------------------------------------------------------------------------
// GEMM: out = 1 + tanh( (A @ W^T - rm) * rsqrt(rv+eps) * g + b )
// ---------------------------------------------------------------------------
__global__ __launch_bounds__(256) void gemm_bn_tanh_k(
    const float* __restrict__ A, const float* __restrict__ W,
    const float* __restrict__ gg, const float* __restrict__ bb,
    const float* __restrict__ rm, const float* __restrict__ rv,
    int M, float* __restrict__ out) {
  __shared__ __align__(16) float As[16][68];
  __shared__ __align__(16) float Bs[16][68];
  const int tid = threadIdx.x;
  const int i0 = blockIdx.x * 64;
  const int j0 = blockIdx.y * 64;
  const int lr = tid >> 2;
  const int lk = (tid & 3) << 2;
  const int tm = tid >> 4;
  const int tn = tid & 15;
  float acc[4][4] = {};
  for (int kt = 0; kt < CCH; kt += 16) {
    float4 av = make_float4(0.f, 0.f, 0.f, 0.f);
    if (i0 + lr < M)
      av = *(const float4*)(A + (size_t)(i0 + lr)*CCH + kt + lk);
    float4 bv = *(const float4*)(W + (size_t)(j0 + lr)*CCH + kt + lk);
    As[lk+0][lr] = av.x; As[lk+1][lr] = av.y; As[lk+2][lr] = av.z; As[lk+3][lr] = av.w;
    Bs[lk+0][lr] = bv.x; Bs[lk+1][lr] = bv.y; Bs[lk+2][lr] = bv.z; Bs[lk+3][lr] = bv.w;
    __syncthreads();
    #pragma unroll
    for (int k = 0; k < 16; ++k) {
      float4 a4 = *(const float4*)&As[k][tm << 2];
      float4 b4 = *(const float4*)&Bs[k][tn << 2];
      float ar[4] = {a4.x, a4.y, a4.z, a4.w};
      float br[4] = {b4.x, b4.y, b4.z, b4.w};
      #pragma unroll
      for (int r = 0; r < 4; ++r)
        #pragma unroll
        for (int c = 0; c < 4; ++c)
          acc[r][c] = fmaf(ar[r], br[c], acc[r][c]);
    }
    __syncthreads();
  }
  float sc[4], sh[4];
  #pragma unroll
  for (int c = 0; c < 4; ++c) {
    int j = j0 + (tn << 2) + c;
    float s = rsqrtf(rv[j] + 1e-5f) * gg[j];
    sc[c] = s;
    sh[c] = bb[j] - rm[j] * s;
  }
  #pragma unroll
  for (int r = 0; r < 4; ++r) {
    int row = i0 + (tm << 2) + r;
    if (row < M) {
      float4 o;
      o.x = 1.f + tanhf(fmaf(acc[r][0], sc[0], sh[0]));
      o.y = 1.f + tanhf(fmaf(acc[r][1], sc[1], sh[1]));
      o.z = 1.f + tanhf(fmaf(acc[r][2], sc[2], sh[2]));
      o.w = 1.f + tanhf(fmaf(acc[r][3], sc[3], sh[3]));
      *(float4*)(out + (size_t)row*CCH + j0 + (tn << 2)) = o;
    }
  }
}

// ---------------------------------------------------------------------------
// GEMM2 fused with combine: wq = 1+tanh(BN(A@W^T)); writes ALL 25 output
// slabs directly: out[w, row, j] = 0.5*wq + 0.5*wprt[w, j].
// A (ndist2) must NOT alias d_out. M = 4096 (multiple of 64).
// ---------------------------------------------------------------------------
__global__ __launch_bounds__(256) void gemm_bn_tanh_combine_k(
    const float* __restrict__ A, const float* __restrict__ W,
    const float* __restrict__ gg, const float* __restrict__ bb,
    const float* __restrict__ rm, const float* __restrict__ rv,
    const float* __restrict__ wprt, float* __restrict__ out) {
  __shared__ __align__(16) float As[16][68];
  __shared__ __align__(16) float Bs[16][68];
  __shared__ float wp_s[WSR][64];    // 0.5*wprt slice for this j-tile
  const int tid = threadIdx.x;
  const int i0 = blockIdx.x * 64;
  const int j0 = blockIdx.y * 64;
  const int lr = tid >> 2;
  const int lk = (tid & 3) << 2;
  const int tm = tid >> 4;
  const int tn = tid & 15;
  float acc[4][4] = {};
  for (int kt = 0; kt < CCH; kt += 16) {
    float4 av = *(const float4*)(A + (size_t)(i0 + lr)*CCH + kt + lk);
    float4 bv = *(const float4*)(W + (size_t)(j0 + lr)*CCH + kt + lk);
    As[lk+0][lr] = av.x; As[lk+1][lr] = av.y; As[lk+2][lr] = av.z; As[lk+3][lr] = av.w;
    Bs[lk+0][lr] = bv.x; Bs[lk+1][lr] = bv.y; Bs[lk+2][lr] = bv.z; Bs[lk+3][lr] = bv.w;
    __syncthreads();
    #pragma unroll
    for (int k = 0; k < 16; ++k) {
      float4 a4 = *(const float4*)&As[k][tm << 2];
      float4 b4 = *(const float4*)&Bs[k][tn << 2];
      float ar[4] = {a4.x, a4.y, a4.z, a4.w};
      float br[4] = {b4.x, b4.y, b4.z, b4.w};
      #pragma unroll
      for (int r = 0; r < 4; ++r)
        #pragma unroll
        for (int c = 0; c < 4; ++c)
          acc[r][c] = fmaf(ar[r], br[c], acc[r][c]);
    }
    __syncthreads();
  }
  // stage 0.5*wprt for this column tile
  for (int idx = tid; idx < WSR*64; idx += 256) {
    int w = idx >> 6, jj = idx & 63;
    wp_s[w][jj] = 0.5f * wprt[w*CCH + j0 + jj];
  }
  float sc[4], sh[4];
  #pragma unroll
  for (int c = 0; c < 4; ++c) {
    int j = j0 + (tn << 2) + c;
    float s = rsqrtf(rv[j] + 1e-5f) * gg[j];
    sc[c] = s;
    sh[c] = bb[j] - rm[j] * s;
  }
  float4 wq[4];
  #pragma unroll
  for (int r = 0; r < 4; ++r) {
    wq[r].x = 0.5f * (1.f + tanhf(fmaf(acc[r][0], sc[0], sh[0])));
    wq[r].y = 0.5f * (1.f + tanhf(fmaf(acc[r][1], sc[1], sh[1])));
    wq[r].z = 0.5f * (1.f + tanhf(fmaf(acc[r][2], sc[2], sh[2])));
    wq[r].w = 0.5f * (1.f + tanhf(fmaf(acc[r][3], sc[3], sh[3])));
  }
  __syncthreads();
  const int jj = tn << 2;
  #pragma unroll 1
  for (int w = 0; w < WSR; ++w) {
    float4 p4 = *(const float4*)&wp_s[w][jj];
    float* base = out + (size_t)w * SLAB + (size_t)(i0 + (tm << 2)) * CCH + j0 + jj;
    #pragma unroll
    for (int r = 0; r < 4; ++r) {
      float4 o;
      o.x = wq[r].x + p4.x; o.y = wq[r].y + p4.y;
      o.z = wq[r].z + p4.z; o.w = wq[r].w + p4.w;
      *(float4*)(base + (size_t)r * CCH) = o;
    }
  }
}

// ---------------------------------------------------------------------------
// pcd: register-resident. 320 threads; thread t owns channels t, t+320.
// ---------------------------------------------------------------------------
__global__ __launch_bounds__(320, 4) void pcd_k(const float* __restrict__ src,
    const float* __restrict__ scl, const float* __restrict__ cw,
    const float* __restrict__ cbp, float* __restrict__ ndist) {
  const int b = blockIdx.x;
  const int t = threadIdx.x;
  __shared__ float xp[320 * MM];     // 32000 B transpose buffer
  __shared__ float part[10][MM];
  __shared__ float pooled[2][MM];
  __shared__ float vbuf[MM];

  const float* row = src + (size_t)b * ROWF;
  const float sc0 = scl[(size_t)b*CCH + t];
  const float sc1 = scl[(size_t)b*CCH + t + 320];

  float x0[MM], x1[MM];
  {
    const float* p0 = row + t * MM;
    const float* p1 = row + (t + 320) * MM;
    float v[4];
    #pragma unroll
    for (int j = 0; j < 6; ++j) {
      load4(v, p0 + 4*j);
      x0[4*j+0] = v[0]*sc0; x0[4*j+1] = v[1]*sc0; x0[4*j+2] = v[2]*sc0; x0[4*j+3] = v[3]*sc0;
    }
    x0[24] = p0[24] * sc0;
    #pragma unroll
    for (int j = 0; j < 6; ++j) {
      load4(v, p1 + 4*j);
      x1[4*j+0] = v[0]*sc1; x1[4*j+1] = v[1]*sc1; x1[4*j+2] = v[2]*sc1; x1[4*j+3] = v[3]*sc1;
    }
    x1[24] = p1[24] * sc1;
  }

  // ---- pooled max ----
  #pragma unroll
  for (int p = 0; p < MM; ++p) xp[t*MM + p] = fmaxf(x0[p], x1[p]);
  __syncthreads();
  if (t < 250) {
    int g = t / MM, p = t - g * MM;
    float m = -3.4e38f;
    #pragma unroll
    for (int k = 0; k < 32; ++k) m = fmaxf(m, xp[(g*32 + k)*MM + p]);
    part[g][p] = m;
  }
  __syncthreads();
  if (t < MM) {
    float m = -3.4e38f;
    #pragma unroll
    for (int g = 0; g < 10; ++g) m = fmaxf(m, part[g][t]);
    pooled[0][t] = m;
  }
  __syncthreads();
  // ---- pooled mean ----
  #pragma unroll
  for (int p = 0; p < MM; ++p) xp[t*MM + p] = x0[p] + x1[p];
  __syncthreads();
  if (t < 250) {
    int g = t / MM, p = t - g * MM;
    float s = 0.f;
    #pragma unroll
    for (int k = 0; k < 32; ++k) s += xp[(g*32 + k)*MM + p];
    part[g][p] = s;
  }
  __syncthreads();
  if (t < MM) {
    float s = 0.f;
    #pragma unroll
    for (int g = 0; g < 10; ++g) s += part[g][t];
    pooled[1][t] = s * (1.f/640.f);
  }
  __syncthreads();
  // ---- 3x3 conv + sigmoid (25 threads) ----
  if (t < MM) {
    int h = t / 5, w_ = t % 5;
    float y = cbp[0];
    #pragma unroll
    for (int ci = 0; ci < 2; ++ci)
      #pragma unroll
      for (int kh = 0; kh < 3; ++kh)
        #pragma unroll
        for (int kw = 0; kw < 3; ++kw) {
          int hh = h + kh - 1, ww = w_ + kw - 1;
          if (hh >= 0 && hh < 5 && ww >= 0 && ww < 5)
            y += pooled[ci][hh*5 + ww] * cw[ci*9 + kh*3 + kw];
        }
    vbuf[t] = 1.f / (1.f + expf(-y));
  }
  __syncthreads();
  // ---- distance from registers ----
  float d0 = 0.f, d1 = 0.f;
  #pragma unroll
  for (int p = 0; p < MM; ++p) {
    float v = vbuf[p];
    float a = x0[p] - v; d0 = fmaf(a, a, d0);
    float e = x1[p] - v; d1 = fmaf(e, e, d1);
  }
  ndist[(size_t)b*CCH + t]       = -d0;
  ndist[(size_t)b*CCH + t + 320] = -d1;
}

// ---------------------------------------------------------------------------
// Fallback combine kernels (used only if d_ws is too small to hold ndist2)
// ---------------------------------------------------------------------------
__global__ __launch_bounds__(256) void combine24_k(const float* __restrict__ wq,
    const float* __restrict__ wp, float* __restrict__ out) {
  const size_t S4 = (size_t)SLAB / 4;
  size_t idx = (size_t)blockIdx.x * 256 + threadIdx.x;
  int slot = (int)(idx / S4);
  size_t rem = idx - (size_t)slot * S4;
  int w = (slot < 3) ? slot : slot + 1;
  int c = (int)((rem * 4) % CCH);
  float4 q = ((const float4*)wq)[rem];
  float4 p = *(const float4*)(wp + w*CCH + c);
  float4 o;
  o.x = 0.5f*(q.x + p.x); o.y = 0.5f*(q.y + p.y);
  o.z = 0.5f*(q.z + p.z); o.w = 0.5f*(q.w + p.w);
  ((float4*)out)[(size_t)w * S4 + rem] = o;
}

__global__ __launch_bounds__(256) void combine3_k(const float* __restrict__ wp,
                                                  float* __restrict__ out) {
  const size_t S4 = (size_t)SLAB / 4;
  size_t rem = (size_t)blockIdx.x * 256 + threadIdx.x;
  int c = (int)((rem * 4) % CCH);
  float4* ptr = (float4*)out + 3 * S4 + rem;
  float4 q = *ptr;
  float4 p = *(const float4*)(wp + 3*CCH + c);
  float4 o;
  o.x = 0.5f*(q.x + p.x); o.y = 0.5f*(q.y + p.y);
  o.z = 0.5f*(q.z + p.z); o.w = 0.5f*(q.w + p.w);
  *ptr = o;
}

// ---------------------------------------------------------------------------
extern "C" void kernel_launch(void* const* d_in, const int* in_sizes, int n_in,
                              void* d_out, int out_size, void* d_ws, size_t ws_size,
                              hipStream_t stream) {
  const float* spt    = (const float*)d_in[0];
  const float* qry    = (const float*)d_in[1];
  const float* W_p    = (const float*)d_in[2];
  const float* g_p    = (const float*)d_in[3];
  const float* b_p    = (const float*)d_in[4];
  const float* rm_p   = (const float*)d_in[5];
  const float* rv_p   = (const float*)d_in[6];
  const float* W_q    = (const float*)d_in[7];
  const float* g_q    = (const float*)d_in[8];
  const float* b_q    = (const float*)d_in[9];
  const float* rm_q   = (const float*)d_in[10];
  const float* rv_q   = (const float*)d_in[11];
  const float* W_prt  = (const float*)d_in[12];
  const float* g_prt  = (const float*)d_in[13];
  const float* b_prt  = (const float*)d_in[14];
  const float* rm_prt = (const float*)d_in[15];
  const float* rv_prt = (const float*)d_in[16];
  const float* W_qs   = (const float*)d_in[17];
  const float* g_qs   = (const float*)d_in[18];
  const float* b_qs   = (const float*)d_in[19];
  const float* rm_qs  = (const float*)d_in[20];
  const float* rv_qs  = (const float*)d_in[21];
  const float* cw_p   = (const float*)d_in[22];
  const float* cb_p   = (const float*)d_in[23];
  const float* cw_q   = (const float*)d_in[24];
  const float* cb_q   = (const float*)d_in[25];

  float* outp = (float*)d_out;
  float* ws   = (float*)d_ws;
  // small proto buffers always fit (we require >= 256KB which any ws has;
  // checked below together with the big buffer)
  const size_t need_fused = (size_t)(64000 + SLAB) * sizeof(float);
  const bool fused = ws_size >= need_fused;

  float* pmean  = ws;
  float* sbuf   = ws + 16000;
  float* ndist1 = ws + 32000;
  float* wprt   = ws + 48000;

  dim3 blk(256);
  dim3 blkp(320);

  if (fused) {
    float* qmean  = outp + 0 * (size_t)SLAB;   // dead before fused GEMM2 writes
    float* qg     = outp + 1 * (size_t)SLAB;   // dead before fused GEMM2 writes
    float* ndist2 = ws + 64000;                // must not alias d_out
    // ---- prototype path ----
    rowmean_k<<<(WSR*CCH + 255)/256, blk, 0, stream>>>(spt, pmean, WSR*CCH);
    gemm_bn_tanh_k<<<dim3(1, CCH/64), blk, 0, stream>>>(pmean, W_p, g_p, b_p, rm_p, rv_p, WSR, sbuf);
    pcd_k<<<WSR, blkp, 0, stream>>>(spt, sbuf, cw_p, cb_p, ndist1);
    gemm_bn_tanh_k<<<dim3(1, CCH/64), blk, 0, stream>>>(ndist1, W_prt, g_prt, b_prt, rm_prt, rv_prt, WSR, wprt);
    // ---- query path ----
    rowmean_k<<<(NB*CCH)/256, blk, 0, stream>>>(qry, qmean, NB*CCH);
    gemm_bn_tanh_k<<<dim3(NB/64, CCH/64), blk, 0, stream>>>(qmean, W_q, g_q, b_q, rm_q, rv_q, NB, qg);
    pcd_k<<<NB, blkp, 0, stream>>>(qry, qg, cw_q, cb_q, ndist2);
    gemm_bn_tanh_combine_k<<<dim3(NB/64, CCH/64), blk, 0, stream>>>(
        ndist2, W_qs, g_qs, b_qs, rm_qs, rv_qs, wprt, outp);
  } else {
    float* qmean  = outp + 0 * (size_t)SLAB;
    float* qg     = outp + 1 * (size_t)SLAB;
    float* ndist2 = outp + 2 * (size_t)SLAB;
    float* wqry   = outp + 3 * (size_t)SLAB;
    rowmean_k<<<(WSR*CCH + 255)/256, blk, 0, stream>>>(spt, pmean, WSR*CCH);
    gemm_bn_tanh_k<<<dim3(1, CCH/64), blk, 0, stream>>>(pmean, W_p, g_p, b_p, rm_p, rv_p, WSR, sbuf);
    pcd_k<<<WSR, blkp, 0, stream>>>(spt, sbuf, cw_p, cb_p, ndist1);
    gemm_bn_tanh_k<<<dim3(1, CCH/64), blk, 0, stream>>>(ndist1, W_prt, g_prt, b_prt, rm_prt, rv_prt, WSR, wprt);
    rowmean_k<<<(NB*CCH)/256, blk, 0, stream>>>(qry, qmean, NB*CCH);
    gemm_bn_tanh_k<<<dim3(NB/64, CCH/64), blk, 0, stream>>>(qmean, W_q, g_q, b_q, rm_q, rv_q, NB, qg);
    pcd_k<<<NB, blkp, 0, stream>>>(qry, qg, cw_q, cb_q, ndist2);
    gemm_bn_tanh_k<<<dim3(NB/64, CCH/64), blk, 0, stream>>>(ndist2, W_qs, g_qs, b_qs, rm_qs, rv_qs, NB, wqry);
    combine24_k<<<(24 * (SLAB/4)) / 256, blk, 0, stream>>>(wqry, wprt, outp);
    combine3_k<<<(SLAB/4) / 256, blk, 0, stream>>>(wprt, outp);
  }
}

// Round 5
// 256.151 us; speedup vs baseline: 1.6369x; 1.6369x over previous
//
#include <hip/hip_runtime.h>
#include <math.h>

// Problem constants
#define CCH   640          // channels
#define MM    25           // m = 5*5 spatial
#define NB    4096         // query batch
#define WSR   25           // way*shot prototype rows
#define ROWF  16000        // CCH*MM floats per row
#define SLAB  (NB*CCH)     // 2,621,440 floats = one output slab (per w)

typedef float fx4 __attribute__((ext_vector_type(4)));

static __device__ __forceinline__ void load4(float* dst, const float* p) {
  __builtin_memcpy(dst, p, 16);
}

// ---------------------------------------------------------------------------
// rowmean_all: one thread per (row,c) over spt rows [0,25) then qry rows.
// ---------------------------------------------------------------------------
__global__ __launch_bounds__(256) void rowmean_all_k(
    const float* __restrict__ spt, const float* __restrict__ qry,
    float* __restrict__ pmean, float* __restrict__ qmean, int n) {
  int idx = blockIdx.x * 256 + threadIdx.x;   // idx = row*CCH + c
  if (idx >= n) return;
  int row = idx / CCH, c = idx - row * CCH;
  const float* p;
  float* dst;
  if (row < WSR) { p = spt + (size_t)row * ROWF + c * MM; dst = pmean + idx; }
  else { p = qry + (size_t)(row - WSR) * ROWF + c * MM; dst = qmean + idx - WSR*CCH; }
  float s = 0.f;
  float v[4];
  #pragma unroll
  for (int j = 0; j < 6; ++j) {
    load4(v, p + 4*j);
    s += (v[0] + v[1]) + (v[2] + v[3]);
  }
  s += p[24];
  *dst = s * (1.f/25.f);
}

// ---------------------------------------------------------------------------
// gemm2_k: two GEMMs in one launch. Blocks [0,10): proto (M0 rows);
// blocks [10,650): query (M1 rows, 64x10 tiles).
// out = 1 + tanh( (A @ W^T - rm) * rsqrt(rv+eps) * g + b )
// ---------------------------------------------------------------------------
__global__ __launch_bounds__(256) void gemm2_k(
    const float* __restrict__ A0, const float* __restrict__ W0,
    const float* __restrict__ g0, const float* __restrict__ b0,
    const float* __restrict__ rm0, const float* __restrict__ rv0,
    int M0, float* __restrict__ out0,
    const float* __restrict__ A1, const float* __restrict__ W1,
    const float* __restrict__ g1, const float* __restrict__ b1,
    const float* __restrict__ rm1, const float* __restrict__ rv1,
    int M1, float* __restrict__ out1) {
  __shared__ __align__(16) float As[16][68];
  __shared__ __align__(16) float Bs[16][68];
  const int bid = blockIdx.x;
  const float *A, *W, *gg, *bb, *rm, *rv;
  float* out;
  int M, i0, j0;
  if (bid < 10) {
    A = A0; W = W0; gg = g0; bb = b0; rm = rm0; rv = rv0; out = out0; M = M0;
    i0 = 0; j0 = bid * 64;
  } else {
    int b2 = bid - 10;
    A = A1; W = W1; gg = g1; bb = b1; rm = rm1; rv = rv1; out = out1; M = M1;
    i0 = (b2 / 10) * 64; j0 = (b2 % 10) * 64;
  }
  const int tid = threadIdx.x;
  const int lr = tid >> 2;
  const int lk = (tid & 3) << 2;
  const int tm = tid >> 4;
  const int tn = tid & 15;
  float acc[4][4] = {};
  for (int kt = 0; kt < CCH; kt += 16) {
    float4 av = make_float4(0.f, 0.f, 0.f, 0.f);
    if (i0 + lr < M)
      av = *(const float4*)(A + (size_t)(i0 + lr)*CCH + kt + lk);
    float4 bv = *(const float4*)(W + (size_t)(j0 + lr)*CCH + kt + lk);
    As[lk+0][lr] = av.x; As[lk+1][lr] = av.y; As[lk+2][lr] = av.z; As[lk+3][lr] = av.w;
    Bs[lk+0][lr] = bv.x; Bs[lk+1][lr] = bv.y; Bs[lk+2][lr] = bv.z; Bs[lk+3][lr] = bv.w;
    __syncthreads();
    #pragma unroll
    for (int k = 0; k < 16; ++k) {
      float4 a4 = *(const float4*)&As[k][tm << 2];
      float4 b4 = *(const float4*)&Bs[k][tn << 2];
      float ar[4] = {a4.x, a4.y, a4.z, a4.w};
      float br[4] = {b4.x, b4.y, b4.z, b4.w};
      #pragma unroll
      for (int r = 0; r < 4; ++r)
        #pragma unroll
        for (int c = 0; c < 4; ++c)
          acc[r][c] = fmaf(ar[r], br[c], acc[r][c]);
    }
    __syncthreads();
  }
  float sc[4], sh[4];
  #pragma unroll
  for (int c = 0; c < 4; ++c) {
    int j = j0 + (tn << 2) + c;
    float s = rsqrtf(rv[j] + 1e-5f) * gg[j];
    sc[c] = s;
    sh[c] = bb[j] - rm[j] * s;
  }
  #pragma unroll
  for (int r = 0; r < 4; ++r) {
    int row = i0 + (tm << 2) + r;
    if (row < M) {
      float4 o;
      o.x = 1.f + tanhf(fmaf(acc[r][0], sc[0], sh[0]));
      o.y = 1.f + tanhf(fmaf(acc[r][1], sc[1], sh[1]));
      o.z = 1.f + tanhf(fmaf(acc[r][2], sc[2], sh[2]));
      o.w = 1.f + tanhf(fmaf(acc[r][3], sc[3], sh[3]));
      *(float4*)(out + (size_t)row*CCH + j0 + (tn << 2)) = o;
    }
  }
}

// ---------------------------------------------------------------------------
// pcd_all: register-resident. Blocks [0,25): proto rows; [25,25+NB): qry rows.
// 320 threads; thread t owns channels t, t+320 (50 gated floats in VGPRs).
// ---------------------------------------------------------------------------
__global__ __launch_bounds__(320, 4) void pcd_all_k(
    const float* __restrict__ spt, const float* __restrict__ qry,
    const float* __restrict__ sbuf, const float* __restrict__ qg,
    const float* __restrict__ cw_p, const float* __restrict__ cb_p,
    const float* __restrict__ cw_q, const float* __restrict__ cb_q,
    float* __restrict__ nd1, float* __restrict__ nd2) {
  const int blk = blockIdx.x;
  const int t = threadIdx.x;
  const float *row, *scl, *cw, *cbp;
  float* ndist;
  if (blk < WSR) {
    row = spt + (size_t)blk * ROWF; scl = sbuf + (size_t)blk * CCH;
    cw = cw_p; cbp = cb_p; ndist = nd1 + (size_t)blk * CCH;
  } else {
    int b = blk - WSR;
    row = qry + (size_t)b * ROWF; scl = qg + (size_t)b * CCH;
    cw = cw_q; cbp = cb_q; ndist = nd2 + (size_t)b * CCH;
  }
  __shared__ float xp[320 * MM];     // 32000 B transpose buffer
  __shared__ float part[10][MM];
  __shared__ float pooled[2][MM];
  __shared__ float vbuf[MM];

  const float sc0 = scl[t];
  const float sc1 = scl[t + 320];

  float x0[MM], x1[MM];
  {
    const float* p0 = row + t * MM;
    const float* p1 = row + (t + 320) * MM;
    float v[4];
    #pragma unroll
    for (int j = 0; j < 6; ++j) {
      load4(v, p0 + 4*j);
      x0[4*j+0] = v[0]*sc0; x0[4*j+1] = v[1]*sc0; x0[4*j+2] = v[2]*sc0; x0[4*j+3] = v[3]*sc0;
    }
    x0[24] = p0[24] * sc0;
    #pragma unroll
    for (int j = 0; j < 6; ++j) {
      load4(v, p1 + 4*j);
      x1[4*j+0] = v[0]*sc1; x1[4*j+1] = v[1]*sc1; x1[4*j+2] = v[2]*sc1; x1[4*j+3] = v[3]*sc1;
    }
    x1[24] = p1[24] * sc1;
  }

  // ---- pooled max ----
  #pragma unroll
  for (int p = 0; p < MM; ++p) xp[t*MM + p] = fmaxf(x0[p], x1[p]);
  __syncthreads();
  if (t < 250) {
    int g = t / MM, p = t - g * MM;
    float m = -3.4e38f;
    #pragma unroll
    for (int k = 0; k < 32; ++k) m = fmaxf(m, xp[(g*32 + k)*MM + p]);
    part[g][p] = m;
  }
  __syncthreads();
  if (t < MM) {
    float m = -3.4e38f;
    #pragma unroll
    for (int g = 0; g < 10; ++g) m = fmaxf(m, part[g][t]);
    pooled[0][t] = m;
  }
  __syncthreads();
  // ---- pooled mean ----
  #pragma unroll
  for (int p = 0; p < MM; ++p) xp[t*MM + p] = x0[p] + x1[p];
  __syncthreads();
  if (t < 250) {
    int g = t / MM, p = t - g * MM;
    float s = 0.f;
    #pragma unroll
    for (int k = 0; k < 32; ++k) s += xp[(g*32 + k)*MM + p];
    part[g][p] = s;
  }
  __syncthreads();
  if (t < MM) {
    float s = 0.f;
    #pragma unroll
    for (int g = 0; g < 10; ++g) s += part[g][t];
    pooled[1][t] = s * (1.f/640.f);
  }
  __syncthreads();
  // ---- 3x3 conv + sigmoid (25 threads) ----
  if (t < MM) {
    int h = t / 5, w_ = t % 5;
    float y = cbp[0];
    #pragma unroll
    for (int ci = 0; ci < 2; ++ci)
      #pragma unroll
      for (int kh = 0; kh < 3; ++kh)
        #pragma unroll
        for (int kw = 0; kw < 3; ++kw) {
          int hh = h + kh - 1, ww = w_ + kw - 1;
          if (hh >= 0 && hh < 5 && ww >= 0 && ww < 5)
            y += pooled[ci][hh*5 + ww] * cw[ci*9 + kh*3 + kw];
        }
    vbuf[t] = 1.f / (1.f + expf(-y));
  }
  __syncthreads();
  // ---- distance from registers ----
  float d0 = 0.f, d1 = 0.f;
  #pragma unroll
  for (int p = 0; p < MM; ++p) {
    float v = vbuf[p];
    float a = x0[p] - v; d0 = fmaf(a, a, d0);
    float e = x1[p] - v; d1 = fmaf(e, e, d1);
  }
  ndist[t]       = -d0;
  ndist[t + 320] = -d1;
}

// ---------------------------------------------------------------------------
// combine: out[w,b,c] = 0.5*wqry[b,c] + 0.5*wprt[w,c]; one streaming pass,
// nontemporal stores (output never re-read).
// ---------------------------------------------------------------------------
__global__ __launch_bounds__(256) void combine_k(const float* __restrict__ wq,
    const float* __restrict__ wp, float* __restrict__ out) {
  const unsigned S4 = SLAB / 4;                       // 655360
  unsigned idx = blockIdx.x * 256 + threadIdx.x;      // float4 idx over 25*S4
  unsigned w = idx / S4;
  unsigned rem = idx - w * S4;
  int c = (int)((rem * 4) % CCH);
  fx4 q = ((const fx4*)wq)[rem];
  fx4 p = *(const fx4*)(wp + w*CCH + c);
  fx4 o = 0.5f * (q + p);
  __builtin_nontemporal_store(o, (fx4*)out + idx);
}

// Fallback combines (d_out slab staging) if workspace is too small
__global__ __launch_bounds__(256) void combine24_k(const float* __restrict__ wq,
    const float* __restrict__ wp, float* __restrict__ out) {
  const size_t S4 = (size_t)SLAB / 4;
  size_t idx = (size_t)blockIdx.x * 256 + threadIdx.x;
  int slot = (int)(idx / S4);
  size_t rem = idx - (size_t)slot * S4;
  int w = (slot < 3) ? slot : slot + 1;
  int c = (int)((rem * 4) % CCH);
  float4 q = ((const float4*)wq)[rem];
  float4 p = *(const float4*)(wp + w*CCH + c);
  float4 o;
  o.x = 0.5f*(q.x + p.x); o.y = 0.5f*(q.y + p.y);
  o.z = 0.5f*(q.z + p.z); o.w = 0.5f*(q.w + p.w);
  ((float4*)out)[(size_t)w * S4 + rem] = o;
}

__global__ __launch_bounds__(256) void combine3_k(const float* __restrict__ wp,
                                                  float* __restrict__ out) {
  const size_t S4 = (size_t)SLAB / 4;
  size_t rem = (size_t)blockIdx.x * 256 + threadIdx.x;
  int c = (int)((rem * 4) % CCH);
  float4* ptr = (float4*)out + 3 * S4 + rem;
  float4 q = *ptr;
  float4 p = *(const float4*)(wp + 3*CCH + c);
  float4 o;
  o.x = 0.5f*(q.x + p.x); o.y = 0.5f*(q.y + p.y);
  o.z = 0.5f*(q.z + p.z); o.w = 0.5f*(q.w + p.w);
  *ptr = o;
}

// ---------------------------------------------------------------------------
extern "C" void kernel_launch(void* const* d_in, const int* in_sizes, int n_in,
                              void* d_out, int out_size, void* d_ws, size_t ws_size,
                              hipStream_t stream) {
  const float* spt    = (const float*)d_in[0];
  const float* qry    = (const float*)d_in[1];
  const float* W_p    = (const float*)d_in[2];
  const float* g_p    = (const float*)d_in[3];
  const float* b_p    = (const float*)d_in[4];
  const float* rm_p   = (const float*)d_in[5];
  const float* rv_p   = (const float*)d_in[6];
  const float* W_q    = (const float*)d_in[7];
  const float* g_q    = (const float*)d_in[8];
  const float* b_q    = (const float*)d_in[9];
  const float* rm_q   = (const float*)d_in[10];
  const float* rv_q   = (const float*)d_in[11];
  const float* W_prt  = (const float*)d_in[12];
  const float* g_prt  = (const float*)d_in[13];
  const float* b_prt  = (const float*)d_in[14];
  const float* rm_prt = (const float*)d_in[15];
  const float* rv_prt = (const float*)d_in[16];
  const float* W_qs   = (const float*)d_in[17];
  const float* g_qs   = (const float*)d_in[18];
  const float* b_qs   = (const float*)d_in[19];
  const float* rm_qs  = (const float*)d_in[20];
  const float* rv_qs  = (const float*)d_in[21];
  const float* cw_p   = (const float*)d_in[22];
  const float* cb_p   = (const float*)d_in[23];
  const float* cw_q   = (const float*)d_in[24];
  const float* cb_q   = (const float*)d_in[25];

  float* outp = (float*)d_out;
  float* ws   = (float*)d_ws;

  float* pmean  = ws;                 // 25*640
  float* sbuf   = ws + 16000;         // 25*640
  float* ndist1 = ws + 32000;         // 25*640
  float* wprt   = ws + 48000;         // 25*640
  const size_t need = (size_t)(64000 + 3*SLAB) * sizeof(float);
  const bool big_ws = ws_size >= need;

  dim3 blk(256);
  dim3 blkp(320);
  const int nmean = (WSR + NB) * CCH;

  if (big_ws) {
    float* qmean  = ws + 64000;                  // NB*640
    float* qg     = ws + 64000 + SLAB;           // NB*640
    float* ndist2 = ws + 64000 + 2*(size_t)SLAB; // NB*640
    float* wqry   = qmean;                       // qmean dead after gemm #1
    rowmean_all_k<<<(nmean + 255)/256, blk, 0, stream>>>(spt, qry, pmean, qmean, nmean);
    gemm2_k<<<650, blk, 0, stream>>>(pmean, W_p, g_p, b_p, rm_p, rv_p, WSR, sbuf,
                                     qmean, W_q, g_q, b_q, rm_q, rv_q, NB, qg);
    pcd_all_k<<<WSR + NB, blkp, 0, stream>>>(spt, qry, sbuf, qg,
                                             cw_p, cb_p, cw_q, cb_q, ndist1, ndist2);
    gemm2_k<<<650, blk, 0, stream>>>(ndist1, W_prt, g_prt, b_prt, rm_prt, rv_prt, WSR, wprt,
                                     ndist2, W_qs, g_qs, b_qs, rm_qs, rv_qs, NB, wqry);
    combine_k<<<25 * (SLAB/4) / 256, blk, 0, stream>>>(wqry, wprt, outp);
  } else {
    float* qmean  = outp + 0 * (size_t)SLAB;
    float* qg     = outp + 1 * (size_t)SLAB;
    float* ndist2 = outp + 2 * (size_t)SLAB;
    float* wqry   = outp + 3 * (size_t)SLAB;
    rowmean_all_k<<<(nmean + 255)/256, blk, 0, stream>>>(spt, qry, pmean, qmean, nmean);
    gemm2_k<<<650, blk, 0, stream>>>(pmean, W_p, g_p, b_p, rm_p, rv_p, WSR, sbuf,
                                     qmean, W_q, g_q, b_q, rm_q, rv_q, NB, qg);
    pcd_all_k<<<WSR + NB, blkp, 0, stream>>>(spt, qry, sbuf, qg,
                                             cw_p, cb_p, cw_q, cb_q, ndist1, ndist2);
    gemm2_k<<<650, blk, 0, stream>>>(ndist1, W_prt, g_prt, b_prt, rm_prt, rv_prt, WSR, wprt,
                                     ndist2, W_qs, g_qs, b_qs, rm_qs, rv_qs, NB, wqry);
    combine24_k<<<(24 * (SLAB/4)) / 256, blk, 0, stream>>>(wqry, wprt, outp);
    combine3_k<<<(SLAB/4) / 256, blk, 0, stream>>>(wprt, outp);
  }
}